// Round 9
// baseline (250.252 us; speedup 1.0000x reference)
//
#include <hip/hip_runtime.h>

// Problem constants
#define BATCH   32
#define CDIM    256
#define HWSZ    1024                 // H*W
#define NTOK    32768                // B*H*W
#define KEMB    8192
#define ZQ_SIZE (BATCH * CDIM * HWSZ) // 8388608

typedef short bf16x8 __attribute__((ext_vector_type(8)));
typedef float floatx4 __attribute__((ext_vector_type(4)));

#define MSPLIT 2                 // codebook strips
#define STRIP  (KEMB / MSPLIT)   // 4096 codes per strip (12-bit local index)
#define NCAND  (3 * MSPLIT)      // rescued candidates per token
#define MB8    128               // codes per tile
#define NB8    128               // tokens per block
#define MT8    (STRIP / MB8)     // 32 tiles per strip

// ---------------------------------------------------------------------------
// Fast-path workspace layout (bytes)
#define WS8_ESQ   0ULL           //  8192 f32 exact ||e||^2
#define WS8_EQM   32768ULL       //  8192 f32 ||e||^2*2048 + 2^23 (key bias)
#define WS8_EH    65536ULL       //  8192*256 bf16
#define WS8_ZH    4259840ULL     // 32768*256 bf16 hi ([token][d])
#define WS8_ZL    21037056ULL    // 32768*256 bf16 lo ([token][d])
#define WS8_PART  37814272ULL    // MSPLIT*NTOK uint4 (k1,k2,k3,0)
#define WS8_IDX   39911424ULL    // NTOK i32
#define WS8_TOTAL 40042496ULL

__device__ __forceinline__ unsigned short bf16rne(float f) {
    unsigned int u = __float_as_uint(f);
    return (unsigned short)((u + 0x7fffu + ((u >> 16) & 1u)) >> 16);
}
__device__ __forceinline__ unsigned int packsplit(float f) {
    unsigned int u  = __float_as_uint(f);
    unsigned int hi = (u + 0x7fffu + ((u >> 16) & 1u)) >> 16;
    float rest      = f - __uint_as_float(hi << 16);
    unsigned int u2 = __float_as_uint(rest);
    unsigned int lo = (u2 + 0x7fffu + ((u2 >> 16) & 1u)) >> 16;
    return (hi << 16) | lo;
}
__device__ __forceinline__ unsigned umin32(unsigned a, unsigned b) { return a < b ? a : b; }
__device__ __forceinline__ unsigned umax32(unsigned a, unsigned b) { return a > b ? a : b; }

#define GLOAD_LDS16(g, l) \
    __builtin_amdgcn_global_load_lds((const __attribute__((address_space(1))) void*)(g), \
                                     (__attribute__((address_space(3))) void*)(l), 16, 0, 0)

// ---------------------------------------------------------------------------
// prep: fused splitz (blocks 0..2047) + esqcvt (blocks 2048..4095).
__global__ void prep_kernel(const float* __restrict__ z, const float* __restrict__ emb,
                            float* __restrict__ eSq, float* __restrict__ eqm,
                            unsigned short* __restrict__ eh,
                            unsigned short* __restrict__ zh, unsigned short* __restrict__ zl) {
    __shared__ unsigned int tile[64][65];
    const int t = threadIdx.x;
    if (blockIdx.x < 2048) {
        int b  = blockIdx.x >> 6;
        int r  = blockIdx.x & 63;
        int dt = r >> 4, ht = r & 15;
        #pragma unroll
        for (int i = 0; i < 4; ++i) {
            int u  = t + 256 * i;
            int dr = u >> 4;
            int c4 = (u & 15) * 4;
            float4 v = *(const float4*)&z[(((size_t)(b * 256 + dt * 64 + dr)) << 10) + ht * 64 + c4];
            tile[dr][c4 + 0] = packsplit(v.x);
            tile[dr][c4 + 1] = packsplit(v.y);
            tile[dr][c4 + 2] = packsplit(v.z);
            tile[dr][c4 + 3] = packsplit(v.w);
        }
        __syncthreads();
        #pragma unroll
        for (int i = 0; i < 2; ++i) {
            int u  = t + 256 * i;
            int d8 = u & 7;    // chunk of 8 dims
            int tr = u >> 3;   // token in tile
            unsigned short h8[8], l8[8];
            #pragma unroll
            for (int j = 0; j < 8; ++j) {
                unsigned int p = tile[d8 * 8 + j][tr];
                h8[j] = (unsigned short)(p >> 16);
                l8[j] = (unsigned short)(p & 0xffff);
            }
            size_t off = (size_t)(b * 1024 + ht * 64 + tr) * 256 + dt * 64 + d8 * 8;
            *(uint4*)&zh[off] = *(uint4*)h8;
            *(uint4*)&zl[off] = *(uint4*)l8;
        }
    } else {
        int k    = (blockIdx.x - 2048) * 4 + (t >> 6);
        int lane = t & 63;
        float4 v = *(const float4*)&emb[k * CDIM + lane * 4];
        float s  = v.x * v.x + v.y * v.y + v.z * v.z + v.w * v.w;
        #pragma unroll
        for (int off = 32; off; off >>= 1) s += __shfl_down(s, off);
        ushort4 h = make_ushort4(bf16rne(v.x), bf16rne(v.y), bf16rne(v.z), bf16rne(v.w));
        *(ushort4*)&eh[k * CDIM + lane * 4] = h;
        if (lane == 0) { eSq[k] = s; eqm[k] = s * 2048.0f + 8388608.0f; }
    }
}

// ---------------------------------------------------------------------------
// dist8: 16x16x32 MFMA, B-in-registers, PAIR-wise barrier pipeline.
//   B (128 tok x 256 d bf16) staged once (two 32KB passes) -> 128 VGPRs/lane.
//   A stream: 4 STATIC 16KB buffers (dr0..3 <-> bufs 0/16K/32K/48K). One
//   wait+barrier per PAIR of rounds (64 barriers, half of the per-round
//   scheme): at pair P: s_waitcnt vmcnt(0) [P's loads issued one pair
//   (~2 round-times) earlier -> already landed, wait is free]; s_barrier
//   [also certifies all waves done reading the half we re-issue]; issue
//   pair P+1 (8 loads) into the OTHER 32KB half; 2x(8 ds_read + 32 MFMA).
//   eqm: rolling 2x1KB LDS ring (1KB covers 2 mts), issued one mt-pair
//   ahead by wave 0 only; certified by the per-pair drain. Saves 15KB LDS
//   vs staging the whole strip's eqm.
//   Top-3 packed keys: key_f = esq*2048 - 4096*acc + 2^23;
//   key = (bits<<12) | local_idx (12-bit, strip=4096); 3-op med3 insert.
#define EQOFF 65536u

#define ISSUE_R(rn, bo_) do { \
    const char* ga_ = gA0 + (size_t)((rn) >> 2) * 65536 + (size_t)((rn) & 3) * 128; \
    _Pragma("unroll") \
    for (int j_ = 0; j_ < 4; ++j_) \
        GLOAD_LDS16(ga_ + j_ * 4096, lds + (bo_) + wvOff + j_ * 1024); \
} while (0)

#define MFMA_ROUND(dr_, bo_) do { \
    __builtin_amdgcn_s_setprio(1); \
    _Pragma("unroll") \
    for (int dk_ = 0; dk_ < 2; ++dk_) { \
        const unsigned xoff_ = (bo_) + (((unsigned)(dk_ * 4) + (unsigned)quad) ^ cx) * 16; \
        bf16x8 afr_[4]; \
        _Pragma("unroll") \
        for (int rf_ = 0; rf_ < 4; ++rf_) afr_[rf_] = *(const bf16x8*)(lds + aR[rf_] + xoff_); \
        _Pragma("unroll") \
        for (int rf_ = 0; rf_ < 4; ++rf_) \
            _Pragma("unroll") \
            for (int cf_ = 0; cf_ < 4; ++cf_) \
                acc[rf_][cf_] = __builtin_amdgcn_mfma_f32_16x16x32_bf16(afr_[rf_], bfr[cf_][dr_][dk_], acc[rf_][cf_], 0, 0, 0); \
    } \
    __builtin_amdgcn_s_setprio(0); \
} while (0)

#define TOP3_EPI(mt_) do { \
    const unsigned eqb_ = EQOFF + ((unsigned)(((mt_) >> 1) & 1)) * 1024u + ((unsigned)((mt_) & 1)) * 512u; \
    _Pragma("unroll") \
    for (int rf_ = 0; rf_ < 4; ++rf_) { \
        const unsigned loc_ = (unsigned)(wm * 64 + rf_ * 16 + quad * 4); \
        floatx4 eq = *(const floatx4*)(lds + eqb_ + (loc_ << 2)); \
        const unsigned base_ = (unsigned)((mt_) * MB8) + loc_; \
        _Pragma("unroll") \
        for (int cf_ = 0; cf_ < 4; ++cf_) { \
            _Pragma("unroll") \
            for (int rr_ = 0; rr_ < 4; ++rr_) { \
                float kf = fmaf(acc[rf_][cf_][rr_], -4096.f, eq[rr_]); \
                unsigned key = (__float_as_uint(kf) << 12) | (base_ + (unsigned)rr_); \
                unsigned n2_, n3_; \
                asm("v_med3_u32 %0, %1, %2, %3" : "=v"(n2_) : "v"(key), "v"(k1[cf_]), "v"(k2[cf_])); \
                asm("v_med3_u32 %0, %1, %2, %3" : "=v"(n3_) : "v"(key), "v"(k2[cf_]), "v"(k3[cf_])); \
                k1[cf_] = umin32(k1[cf_], key); \
                k2[cf_] = n2_; \
                k3[cf_] = n3_; \
            } \
        } \
    } \
} while (0)

#define VMW0()  asm volatile("s_waitcnt vmcnt(0)" ::: "memory")
#define BARR()  asm volatile("s_barrier" ::: "memory")

__global__ __launch_bounds__(256, 2)
void dist8_kernel(const unsigned short* __restrict__ zhp,
                  const unsigned short* __restrict__ ehp,
                  const float* __restrict__ eqm,
                  uint4* __restrict__ part) {
    __shared__ __align__(16) char lds[67584];   // 4x16KB A bufs + 2x1KB eq ring

    const int t    = threadIdx.x;
    const int lane = t & 63;
    const int wv   = t >> 6;
    const int wm   = wv >> 1, wn = wv & 1;
    const int l15  = lane & 15, quad = lane >> 4;

    const int nb = blockIdx.x & 255;
    const int q  = blockIdx.x >> 8;
    const int n0 = nb * NB8;
    const int cstrip = q * STRIP;

    // DMA lane pattern: lane -> (row = lane>>3, slot = lane&7), global chunk = slot ^ row
    const int dmaRow  = lane >> 3;
    const int dmaChnk = (lane & 7) ^ dmaRow;
    const unsigned laneGoff = (unsigned)dmaRow * 512 + (unsigned)dmaChnk * 16;

    const char* gA0 = (const char*)ehp + (size_t)(cstrip + wv * 32) * 512 + laneGoff;
    const char* gB0 = (const char*)zhp + (size_t)(n0 + wv * 32) * 512 + laneGoff;
    const unsigned wvOff = (unsigned)wv * 4096;
    const unsigned cx = (unsigned)(l15 & 7);

    bf16x8 bfr[4][4][2];

    // ---- B staging pass 1: d-slices 0,1 (32KB) + eq ring prologue (2x1KB,
    //      covers mts 0..3), wave 0 only
    #pragma unroll
    for (int s = 0; s < 2; ++s)
        #pragma unroll
        for (int j = 0; j < 4; ++j)
            GLOAD_LDS16(gB0 + s * 128 + j * 4096, lds + s * 16384 + wvOff + j * 1024);
    if (wv == 0) {
        #pragma unroll
        for (int j = 0; j < 2; ++j)
            GLOAD_LDS16((const char*)(eqm + cstrip + j * 256) + lane * 16,
                        lds + EQOFF + (unsigned)j * 1024u);
    }
    __syncthreads();
    #pragma unroll
    for (int cf = 0; cf < 4; ++cf) {
        const unsigned bRow = (unsigned)(wn * 64 + cf * 16 + l15) * 128;
        #pragma unroll
        for (int s = 0; s < 2; ++s)
            #pragma unroll
            for (int dk = 0; dk < 2; ++dk)
                bfr[cf][s][dk] = *(const bf16x8*)(lds + s * 16384 + bRow +
                                    (((unsigned)(dk * 4) + (unsigned)quad) ^ cx) * 16);
    }
    __syncthreads();
    // ---- B staging pass 2: d-slices 2,3 reuse buf0/buf1
    #pragma unroll
    for (int s = 0; s < 2; ++s)
        #pragma unroll
        for (int j = 0; j < 4; ++j)
            GLOAD_LDS16(gB0 + (s + 2) * 128 + j * 4096, lds + s * 16384 + wvOff + j * 1024);
    __syncthreads();
    #pragma unroll
    for (int cf = 0; cf < 4; ++cf) {
        const unsigned bRow = (unsigned)(wn * 64 + cf * 16 + l15) * 128;
        #pragma unroll
        for (int s = 0; s < 2; ++s)
            #pragma unroll
            for (int dk = 0; dk < 2; ++dk)
                bfr[cf][s + 2][dk] = *(const bf16x8*)(lds + s * 16384 + bRow +
                                    (((unsigned)(dk * 4) + (unsigned)quad) ^ cx) * 16);
    }
    __syncthreads();   // all B reads drained; LDS bufs now free for A pipeline

    // fragment LDS row bases for A (within a 16KB buffer)
    unsigned aR[4];
    #pragma unroll
    for (int rf = 0; rf < 4; ++rf) aR[rf] = (unsigned)(wm * 64 + rf * 16 + l15) * 128;

    unsigned k1[4], k2[4], k3[4];
    #pragma unroll
    for (int cf = 0; cf < 4; ++cf) { k1[cf] = 0xFFFFFFFFu; k2[cf] = 0xFFFFFFFFu; k3[cf] = 0xFFFFFFFFu; }

    // prologue: pair 0 (rounds 0,1) in flight
    ISSUE_R(0, 0u);
    ISSUE_R(1, 16384u);

    for (int mt = 0; mt < MT8 - 1; ++mt) {
        floatx4 acc[4][4];
        #pragma unroll
        for (int rf = 0; rf < 4; ++rf)
            #pragma unroll
            for (int cf = 0; cf < 4; ++cf) acc[rf][cf] = (floatx4){0.f, 0.f, 0.f, 0.f};

        // pair A: consume rounds 4mt,4mt+1 (bufs 0,16K); issue rounds 4mt+2,+3
        VMW0();
        BARR();
        ISSUE_R(4 * mt + 2, 32768u);
        ISSUE_R(4 * mt + 3, 49152u);
        if (((mt & 1) == 0) && mt >= 2 && mt <= 28 && wv == 0)
            GLOAD_LDS16((const char*)(eqm + cstrip + (mt / 2 + 1) * 256) + lane * 16,
                        lds + EQOFF + (unsigned)(((mt / 2 + 1) & 1)) * 1024u);
        MFMA_ROUND(0, 0u);
        MFMA_ROUND(1, 16384u);

        // pair B: consume rounds 4mt+2,+3 (bufs 32K,48K); issue rounds 4mt+4,+5
        VMW0();
        BARR();
        ISSUE_R(4 * mt + 4, 0u);
        ISSUE_R(4 * mt + 5, 16384u);
        MFMA_ROUND(2, 32768u);
        MFMA_ROUND(3, 49152u);

        TOP3_EPI(mt);
    }
    {   // mt = MT8-1 (drain tail)
        floatx4 acc[4][4];
        #pragma unroll
        for (int rf = 0; rf < 4; ++rf)
            #pragma unroll
            for (int cf = 0; cf < 4; ++cf) acc[rf][cf] = (floatx4){0.f, 0.f, 0.f, 0.f};

        VMW0();
        BARR();
        ISSUE_R(4 * MT8 - 2, 32768u);
        ISSUE_R(4 * MT8 - 1, 49152u);
        MFMA_ROUND(0, 0u);
        MFMA_ROUND(1, 16384u);

        VMW0();
        BARR();
        MFMA_ROUND(2, 32768u);
        MFMA_ROUND(3, 49152u);

        TOP3_EPI(MT8 - 1);
    }

    // merge across row-quads (lanes sharing a token column): xor 16 then xor 32
    #pragma unroll
    for (int cf = 0; cf < 4; ++cf) {
        #pragma unroll
        for (int s = 0; s < 2; ++s) {
            int m = s ? 32 : 16;
            unsigned o1 = (unsigned)__shfl((int)k1[cf], lane ^ m, 64);
            unsigned o2 = (unsigned)__shfl((int)k2[cf], lane ^ m, 64);
            unsigned o3 = (unsigned)__shfl((int)k3[cf], lane ^ m, 64);
            unsigned a1  = umax32(k1[cf], o1);
            k1[cf]       = umin32(k1[cf], o1);
            unsigned b1  = umin32(k2[cf], o2);
            unsigned r3a = umax32(a1, b1);
            k2[cf]       = umin32(a1, b1);
            k3[cf]       = umin32(r3a, umin32(k3[cf], o3));
        }
    }

    __syncthreads();   // staging LDS done; reuse as reduction buffer
    uint4* red = (uint4*)lds;  // 256 entries (wm x 128 tokens)
    if (quad == 0) {
        #pragma unroll
        for (int cf = 0; cf < 4; ++cf)
            red[wm * 128 + wn * 64 + cf * 16 + l15] = make_uint4(k1[cf], k2[cf], k3[cf], 0u);
    }
    __syncthreads();
    if (t < 128) {
        uint4 a = red[t], b = red[128 + t];
        unsigned a1  = umax32(a.x, b.x);
        unsigned r1  = umin32(a.x, b.x);
        unsigned b1  = umin32(a.y, b.y);
        unsigned r3a = umax32(a1, b1);
        unsigned r2  = umin32(a1, b1);
        unsigned r3  = umin32(r3a, umin32(a.z, b.z));
        part[q * NTOK + n0 + t] = make_uint4(r1, r2, r3, 0u);
    }
}

// ---------------------------------------------------------------------------
// Rescore NCAND (=6) strip candidates (2 strips x top-3) with near-exact fp32
// (z = hi+lo bf16 pair, error <= 2^-18 |z|); numpy tie-break.
__global__ void rescore12_kernel(const unsigned short* __restrict__ zh,
                                 const unsigned short* __restrict__ zl,
                                 const float* __restrict__ emb,
                                 const float* __restrict__ eSq, const uint4* __restrict__ part,
                                 int* __restrict__ idx, float* __restrict__ idxF) {
    int n    = blockIdx.x * 4 + (threadIdx.x >> 6);
    int lane = threadIdx.x & 63;
    int c[NCAND];
    #pragma unroll
    for (int s = 0; s < MSPLIT; ++s) {
        uint4 p = part[s * NTOK + n];
        c[3 * s]     = s * STRIP + (int)(p.x & 0xFFFu);
        c[3 * s + 1] = s * STRIP + (int)(p.y & 0xFFFu);
        c[3 * s + 2] = s * STRIP + (int)(p.z & 0xFFFu);
    }
    // reconstruct 4 contiguous dims of z for this lane (hi+lo pair)
    ushort4 h = *(const ushort4*)&zh[(size_t)n * CDIM + lane * 4];
    ushort4 l = *(const ushort4*)&zl[(size_t)n * CDIM + lane * 4];
    float z0 = __uint_as_float((unsigned)h.x << 16) + __uint_as_float((unsigned)l.x << 16);
    float z1 = __uint_as_float((unsigned)h.y << 16) + __uint_as_float((unsigned)l.y << 16);
    float z2 = __uint_as_float((unsigned)h.z << 16) + __uint_as_float((unsigned)l.z << 16);
    float z3 = __uint_as_float((unsigned)h.w << 16) + __uint_as_float((unsigned)l.w << 16);
    float acc[NCAND];
    #pragma unroll
    for (int s = 0; s < NCAND; ++s) {
        float4 e = *(const float4*)&emb[(size_t)c[s] * CDIM + lane * 4];
        acc[s] = fmaf(z0, e.x, fmaf(z1, e.y, fmaf(z2, e.z, z3 * e.w)));
    }
    #pragma unroll
    for (int off = 32; off; off >>= 1) {
        #pragma unroll
        for (int s = 0; s < NCAND; ++s) acc[s] += __shfl_down(acc[s], off);
    }
    if (lane == 0) {
        float bd = 3.4e38f; int bi = 0x7fffffff;
        #pragma unroll
        for (int s = 0; s < NCAND; ++s) {
            float dv = eSq[c[s]] - 2.f * acc[s];
            if (dv < bd || (dv == bd && c[s] < bi)) { bd = dv; bi = c[s]; }
        }
        idx[n]  = bi;
        idxF[n] = (float)bi;
    }
}

// ---------------------------------------------------------------------------
// gather2: coalesced emb reads, LDS transpose, coalesced BCHW writes
__global__ void gather2_kernel(const float* __restrict__ emb, const int* __restrict__ idx,
                               float* __restrict__ out) {
    __shared__ float tile[32 * 260];
    __shared__ int rows[32];
    const int t  = threadIdx.x;
    const int n0 = blockIdx.x * 32;
    if (t < 32) rows[t] = idx[n0 + t];
    __syncthreads();
    {
        int r  = t >> 3;
        int c0 = (t & 7) * 32;
        const float* src = emb + (size_t)rows[r] * CDIM + c0;
        #pragma unroll
        for (int j = 0; j < 8; ++j) {
            float4 v = *(const float4*)(src + j * 4);
            *(float4*)&tile[r * 260 + c0 + j * 4] = v;
        }
    }
    __syncthreads();
    const int b   = n0 >> 10;
    const int hw0 = n0 & 1023;
    const int cg  = t >> 3;         // 0..31
    const int h4  = (t & 7) * 4;    // 0..28
    #pragma unroll
    for (int j = 0; j < 8; ++j) {
        int c = cg + j * 32;
        float4 v;
        v.x = tile[(h4 + 0) * 260 + c];
        v.y = tile[(h4 + 1) * 260 + c];
        v.z = tile[(h4 + 2) * 260 + c];
        v.w = tile[(h4 + 3) * 260 + c];
        *(float4*)&out[((size_t)b << 18) | ((size_t)c << 10) | (size_t)(hw0 + h4)] = v;
    }
}

// ---------------------------------------------------------------------------
// Fallback: round-1 fp32 path (used only if ws is too small for fast path)
#define F_BM  128
#define F_BK  128
#define F_BD  32
#define F_BSS (F_BK + 4)
#define F_KSPLIT 4
#define F_KPER  (KEMB / F_KSPLIT)
#define FWS_ESQ 0
#define FWS_PV  32768
#define FWS_PI  557056
#define FWS_IDX 1081344

__global__ void esq_kernel(const float* __restrict__ emb, float* __restrict__ eSq) {
    int k    = blockIdx.x * 4 + (threadIdx.x >> 6);
    int lane = threadIdx.x & 63;
    float4 v = *(const float4*)&emb[k * CDIM + lane * 4];
    float s  = v.x * v.x + v.y * v.y + v.z * v.z + v.w * v.w;
    #pragma unroll
    for (int off = 32; off; off >>= 1) s += __shfl_down(s, off);
    if (lane == 0) eSq[k] = s;
}

__global__ void dist_kernel(const float* __restrict__ z, const float* __restrict__ emb,
                            const float* __restrict__ eSq,
                            float* __restrict__ pv, int* __restrict__ pi) {
    __shared__ __align__(16) char smem[(F_BD * F_BM + F_BD * F_BSS) * 4];
    float (*As)[F_BM]  = (float (*)[F_BM])smem;
    float (*Bs)[F_BSS] = (float (*)[F_BSS])(smem + F_BD * F_BM * 4);
    const int t = threadIdx.x, tx = t & 15, ty = t >> 4;
    const int rb = blockIdx.x & 255, q = blockIdx.x >> 8;
    const int m0 = rb * F_BM, bb = m0 >> 10, hw0 = m0 & 1023;
    float minv[8]; int mini[8];
    #pragma unroll
    for (int i = 0; i < 8; ++i) { minv[i] = 3.4028235e38f; mini[i] = 0; }
    const int kbeg = q * F_KPER;
    for (int k0 = kbeg; k0 < kbeg + F_KPER; k0 += F_BK) {
        float acc[8][8];
        #pragma unroll
        for (int r = 0; r < 8; ++r)
            #pragma unroll
            for (int c = 0; c < 8; ++c) acc[r][c] = 0.f;
        for (int d0 = 0; d0 < CDIM; d0 += F_BD) {
            __syncthreads();
            #pragma unroll
            for (int i = 0; i < 4; ++i) {
                int u = t + i * 256; int m4 = (u & 31) << 2; int cR = u >> 5;
                float4 v = *(const float4*)&z[(bb << 18) + ((d0 + cR) << 10) + hw0 + m4];
                *(float4*)&As[cR][m4] = v;
            }
            #pragma unroll
            for (int i = 0; i < 4; ++i) {
                int u = t + i * 256; int kR = u >> 3; int c4 = (u & 7) << 2;
                float4 v = *(const float4*)&emb[(k0 + kR) * CDIM + d0 + c4];
                Bs[c4 + 0][kR] = v.x; Bs[c4 + 1][kR] = v.y;
                Bs[c4 + 2][kR] = v.z; Bs[c4 + 3][kR] = v.w;
            }
            __syncthreads();
            #pragma unroll
            for (int d = 0; d < F_BD; ++d) {
                float a[8], bb2[8];
                *(float4*)&a[0] = *(const float4*)&As[d][(ty << 2)];
                *(float4*)&a[4] = *(const float4*)&As[d][64 + (ty << 2)];
                *(float4*)&bb2[0] = *(const float4*)&Bs[d][(tx << 2)];
                *(float4*)&bb2[4] = *(const float4*)&Bs[d][64 + (tx << 2)];
                #pragma unroll
                for (int r = 0; r < 8; ++r)
                    #pragma unroll
                    for (int c = 0; c < 8; ++c) acc[r][c] = fmaf(a[r], bb2[c], acc[r][c]);
            }
        }
        #pragma unroll
        for (int c = 0; c < 8; ++c) {
            int kk = (c < 4) ? ((tx << 2) + c) : (64 + (tx << 2) + (c - 4));
            int kg = k0 + kk;
            float es = eSq[kg];
            #pragma unroll
            for (int r = 0; r < 8; ++r) {
                float v = fmaf(-2.f, acc[r][c], es);
                if (v < minv[r]) { minv[r] = v; mini[r] = kg; }
            }
        }
    }
    __syncthreads();
    float (*redV)[16] = (float (*)[16])smem;
    int   (*redI)[16] = (int   (*)[16])(smem + F_BM * 16 * 4);
    #pragma unroll
    for (int r = 0; r < 8; ++r) {
        int row = (r < 4) ? ((ty << 2) + r) : (64 + (ty << 2) + (r - 4));
        redV[row][tx] = minv[r]; redI[row][tx] = mini[r];
    }
    __syncthreads();
    if (t < F_BM) {
        float bv = redV[t][0]; int bi = redI[t][0];
        #pragma unroll
        for (int i = 1; i < 16; ++i) {
            float v = redV[t][i]; int ii = redI[t][i];
            if (v < bv || (v == bv && ii < bi)) { bv = v; bi = ii; }
        }
        int n = m0 + t;
        pv[q * NTOK + n] = bv; pi[q * NTOK + n] = bi;
    }
}

__global__ void merge_kernel(const float* __restrict__ pv, const int* __restrict__ pi,
                             int* __restrict__ idxOut, float* __restrict__ idxFOut) {
    int n = blockIdx.x * 256 + threadIdx.x;
    float bv = pv[n]; int bi = pi[n];
    #pragma unroll
    for (int q = 1; q < F_KSPLIT; ++q) {
        float v = pv[q * NTOK + n]; int ii = pi[q * NTOK + n];
        if (v < bv || (v == bv && ii < bi)) { bv = v; bi = ii; }
    }
    idxOut[n] = bi; idxFOut[n] = (float)bi;
}

// ---------------------------------------------------------------------------
extern "C" void kernel_launch(void* const* d_in, const int* in_sizes, int n_in,
                              void* d_out, int out_size, void* d_ws, size_t ws_size,
                              hipStream_t stream) {
    const float* z   = (const float*)d_in[0];
    const float* emb = (const float*)d_in[1];
    float* out = (float*)d_out;
    char*  ws  = (char*)d_ws;

    if (ws_size >= WS8_TOTAL) {
        float*          eSq  = (float*)(ws + WS8_ESQ);
        float*          eqm  = (float*)(ws + WS8_EQM);
        unsigned short* eh   = (unsigned short*)(ws + WS8_EH);
        unsigned short* zh   = (unsigned short*)(ws + WS8_ZH);
        unsigned short* zl   = (unsigned short*)(ws + WS8_ZL);
        uint4*          part = (uint4*)(ws + WS8_PART);
        int*            idx  = (int*)(ws + WS8_IDX);

        prep_kernel   <<<4096, 256, 0, stream>>>(z, emb, eSq, eqm, eh, zh, zl);
        dist8_kernel  <<<256 * MSPLIT, 256, 0, stream>>>(zh, eh, eqm, part);
        rescore12_kernel<<<NTOK / 4, 256, 0, stream>>>(zh, zl, emb, eSq, part, idx, out + ZQ_SIZE);
        gather2_kernel<<<NTOK / 32, 256, 0, stream>>>(emb, idx, out);
    } else {
        float* eSq = (float*)(ws + FWS_ESQ);
        float* pv  = (float*)(ws + FWS_PV);
        int*   pi  = (int*)(ws + FWS_PI);
        int*   idx = (int*)(ws + FWS_IDX);
        esq_kernel  <<<KEMB / 4, 256, 0, stream>>>(emb, eSq);
        dist_kernel <<<256 * F_KSPLIT, 256, 0, stream>>>(z, emb, eSq, pv, pi);
        merge_kernel<<<NTOK / 256, 256, 0, stream>>>(pv, pi, idx, out + ZQ_SIZE);
        gather2_kernel<<<NTOK / 32, 256, 0, stream>>>(emb, idx, out);
    }
}

// Round 11
// 247.551 us; speedup vs baseline: 1.0109x; 1.0109x over previous
//
#include <hip/hip_runtime.h>

// Problem constants
#define BATCH   32
#define CDIM    256
#define HWSZ    1024                 // H*W
#define NTOK    32768                // B*H*W
#define KEMB    8192
#define ZQ_SIZE (BATCH * CDIM * HWSZ) // 8388608

typedef short bf16x8 __attribute__((ext_vector_type(8)));
typedef float floatx4 __attribute__((ext_vector_type(4)));

#define MSPLIT 2                 // codebook strips
#define STRIP  (KEMB / MSPLIT)   // 4096 codes per strip (12-bit local index)
#define NCAND  (3 * MSPLIT)      // rescued candidates per token
#define MB8    128               // codes per tile
#define NB8    128               // tokens per block
#define MT8    (STRIP / MB8)     // 32 tiles per strip

// ---------------------------------------------------------------------------
// Fast-path workspace layout (bytes)
#define WS8_ESQ   0ULL           //  8192 f32 exact ||e||^2
#define WS8_EQM   32768ULL       //  8192 f32 ||e||^2*2048 + 2^23 (key bias)
#define WS8_EH    65536ULL       //  8192*256 bf16
#define WS8_ZH    4259840ULL     // 32768*256 bf16 hi ([token][d])
#define WS8_ZL    21037056ULL    // 32768*256 bf16 lo ([token][d])
#define WS8_PART  37814272ULL    // MSPLIT*NTOK uint4 (k1,k2,k3,0)
#define WS8_IDX   39911424ULL    // NTOK i32 (unused in fast path; kept for layout)
#define WS8_TOTAL 40042496ULL

__device__ __forceinline__ unsigned short bf16rne(float f) {
    unsigned int u = __float_as_uint(f);
    return (unsigned short)((u + 0x7fffu + ((u >> 16) & 1u)) >> 16);
}
__device__ __forceinline__ unsigned int packsplit(float f) {
    unsigned int u  = __float_as_uint(f);
    unsigned int hi = (u + 0x7fffu + ((u >> 16) & 1u)) >> 16;
    float rest      = f - __uint_as_float(hi << 16);
    unsigned int u2 = __float_as_uint(rest);
    unsigned int lo = (u2 + 0x7fffu + ((u2 >> 16) & 1u)) >> 16;
    return (hi << 16) | lo;
}
__device__ __forceinline__ unsigned umin32(unsigned a, unsigned b) { return a < b ? a : b; }
__device__ __forceinline__ unsigned umax32(unsigned a, unsigned b) { return a > b ? a : b; }

#define GLOAD_LDS16(g, l) \
    __builtin_amdgcn_global_load_lds((const __attribute__((address_space(1))) void*)(g), \
                                     (__attribute__((address_space(3))) void*)(l), 16, 0, 0)

// ---------------------------------------------------------------------------
// prep: fused splitz (blocks 0..2047) + esqcvt (blocks 2048..4095).
__global__ void prep_kernel(const float* __restrict__ z, const float* __restrict__ emb,
                            float* __restrict__ eSq, float* __restrict__ eqm,
                            unsigned short* __restrict__ eh,
                            unsigned short* __restrict__ zh, unsigned short* __restrict__ zl) {
    __shared__ unsigned int tile[64][65];
    const int t = threadIdx.x;
    if (blockIdx.x < 2048) {
        int b  = blockIdx.x >> 6;
        int r  = blockIdx.x & 63;
        int dt = r >> 4, ht = r & 15;
        #pragma unroll
        for (int i = 0; i < 4; ++i) {
            int u  = t + 256 * i;
            int dr = u >> 4;
            int c4 = (u & 15) * 4;
            float4 v = *(const float4*)&z[(((size_t)(b * 256 + dt * 64 + dr)) << 10) + ht * 64 + c4];
            tile[dr][c4 + 0] = packsplit(v.x);
            tile[dr][c4 + 1] = packsplit(v.y);
            tile[dr][c4 + 2] = packsplit(v.z);
            tile[dr][c4 + 3] = packsplit(v.w);
        }
        __syncthreads();
        #pragma unroll
        for (int i = 0; i < 2; ++i) {
            int u  = t + 256 * i;
            int d8 = u & 7;    // chunk of 8 dims
            int tr = u >> 3;   // token in tile
            unsigned short h8[8], l8[8];
            #pragma unroll
            for (int j = 0; j < 8; ++j) {
                unsigned int p = tile[d8 * 8 + j][tr];
                h8[j] = (unsigned short)(p >> 16);
                l8[j] = (unsigned short)(p & 0xffff);
            }
            size_t off = (size_t)(b * 1024 + ht * 64 + tr) * 256 + dt * 64 + d8 * 8;
            *(uint4*)&zh[off] = *(uint4*)h8;
            *(uint4*)&zl[off] = *(uint4*)l8;
        }
    } else {
        int k    = (blockIdx.x - 2048) * 4 + (t >> 6);
        int lane = t & 63;
        float4 v = *(const float4*)&emb[k * CDIM + lane * 4];
        float s  = v.x * v.x + v.y * v.y + v.z * v.z + v.w * v.w;
        #pragma unroll
        for (int off = 32; off; off >>= 1) s += __shfl_down(s, off);
        ushort4 h = make_ushort4(bf16rne(v.x), bf16rne(v.y), bf16rne(v.z), bf16rne(v.w));
        *(ushort4*)&eh[k * CDIM + lane * 4] = h;
        if (lane == 0) { eSq[k] = s; eqm[k] = s * 2048.0f + 8388608.0f; }
    }
}

// ---------------------------------------------------------------------------
// dist8: 16x16x32 MFMA, B-in-registers + counted-vmcnt pipeline (R8 core).
//   B (128 tok x 256 d bf16) staged once (two 32KB passes) -> 128 VGPRs/lane.
//   eqm strip (16KB) staged to LDS so the epilogue issues NO vmem ops.
//   Main loop: 3 x 16KB A buffers; per round (128 total):
//     s_waitcnt vmcnt(4); s_barrier; issue round r+2 DMA; 8 ds_read + 32 MFMA.
//   vmcnt never drains to 0 until the last round. setprio dropped (T5 is
//   null-to-negative on lockstep barrier-synced structures, m190).
//   Top-3 packed keys: key_f = esq*2048 - 4096*acc + 2^23;
//   key = (bits(key_f)<<12) | local_idx (12-bit, strip=4096).
//   3-op sorted insert via v_med3_u32.
#define EQOFF 49152u

#define ISSUE_A(rn, bo_) do { \
    const char* ga_ = gA0 + (size_t)((rn) >> 2) * 65536 + (size_t)((rn) & 3) * 128; \
    _Pragma("unroll") \
    for (int j_ = 0; j_ < 4; ++j_) \
        GLOAD_LDS16(ga_ + j_ * 4096, lds + (bo_) + wvOff + j_ * 1024); \
} while (0)

#define MFMA_ROUND(dr_, bo_) do { \
    _Pragma("unroll") \
    for (int dk_ = 0; dk_ < 2; ++dk_) { \
        const unsigned xoff_ = (bo_) + (((unsigned)(dk_ * 4) + (unsigned)quad) ^ cx) * 16; \
        bf16x8 afr_[4]; \
        _Pragma("unroll") \
        for (int rf_ = 0; rf_ < 4; ++rf_) afr_[rf_] = *(const bf16x8*)(lds + aR[rf_] + xoff_); \
        _Pragma("unroll") \
        for (int rf_ = 0; rf_ < 4; ++rf_) \
            _Pragma("unroll") \
            for (int cf_ = 0; cf_ < 4; ++cf_) \
                acc[rf_][cf_] = __builtin_amdgcn_mfma_f32_16x16x32_bf16(afr_[rf_], bfr[cf_][dr_][dk_], acc[rf_][cf_], 0, 0, 0); \
    } \
} while (0)

#define TOP3_EPI(mt_) do { \
    _Pragma("unroll") \
    for (int rf_ = 0; rf_ < 4; ++rf_) { \
        const unsigned base_ = (unsigned)((mt_) * MB8 + wm * 64 + rf_ * 16 + quad * 4); \
        floatx4 eq = *(const floatx4*)(lds + EQOFF + (base_ << 2)); \
        _Pragma("unroll") \
        for (int cf_ = 0; cf_ < 4; ++cf_) { \
            _Pragma("unroll") \
            for (int rr_ = 0; rr_ < 4; ++rr_) { \
                float kf = fmaf(acc[rf_][cf_][rr_], -4096.f, eq[rr_]); \
                unsigned key = (__float_as_uint(kf) << 12) | (base_ + (unsigned)rr_); \
                unsigned n2_, n3_; \
                asm("v_med3_u32 %0, %1, %2, %3" : "=v"(n2_) : "v"(key), "v"(k1[cf_]), "v"(k2[cf_])); \
                asm("v_med3_u32 %0, %1, %2, %3" : "=v"(n3_) : "v"(key), "v"(k2[cf_]), "v"(k3[cf_])); \
                k1[cf_] = umin32(k1[cf_], key); \
                k2[cf_] = n2_; \
                k3[cf_] = n3_; \
            } \
        } \
    } \
} while (0)

#define VMW4()  asm volatile("s_waitcnt vmcnt(4)" ::: "memory")
#define VMW0()  asm volatile("s_waitcnt vmcnt(0)" ::: "memory")
#define BARR()  asm volatile("s_barrier" ::: "memory")

__global__ __launch_bounds__(256, 2)
void dist8_kernel(const unsigned short* __restrict__ zhp,
                  const unsigned short* __restrict__ ehp,
                  const float* __restrict__ eqm,
                  uint4* __restrict__ part) {
    __shared__ __align__(16) char lds[65536];   // 3x16KB A bufs + 16KB eqm

    const int t    = threadIdx.x;
    const int lane = t & 63;
    const int wv   = t >> 6;
    const int wm   = wv >> 1, wn = wv & 1;
    const int l15  = lane & 15, quad = lane >> 4;

    const int nb = blockIdx.x & 255;
    const int q  = blockIdx.x >> 8;
    const int n0 = nb * NB8;
    const int cstrip = q * STRIP;

    // DMA lane pattern: lane -> (row = lane>>3, slot = lane&7), global chunk = slot ^ row
    const int dmaRow  = lane >> 3;
    const int dmaChnk = (lane & 7) ^ dmaRow;
    const unsigned laneGoff = (unsigned)dmaRow * 512 + (unsigned)dmaChnk * 16;

    const char* gA0 = (const char*)ehp + (size_t)(cstrip + wv * 32) * 512 + laneGoff;
    const char* gB0 = (const char*)zhp + (size_t)(n0 + wv * 32) * 512 + laneGoff;
    const unsigned wvOff = (unsigned)wv * 4096;
    const unsigned cx = (unsigned)(l15 & 7);

    bf16x8 bfr[4][4][2];

    // ---- B staging pass 1: d-slices 0,1 (32KB) + eqm strip (16KB, linear)
    #pragma unroll
    for (int s = 0; s < 2; ++s)
        #pragma unroll
        for (int j = 0; j < 4; ++j)
            GLOAD_LDS16(gB0 + s * 128 + j * 4096, lds + s * 16384 + wvOff + j * 1024);
    #pragma unroll
    for (int j = 0; j < 4; ++j)
        GLOAD_LDS16((const char*)(eqm + cstrip) + wv * 4096 + j * 1024 + lane * 16,
                    lds + EQOFF + (unsigned)wv * 4096 + (unsigned)j * 1024);
    __syncthreads();
    #pragma unroll
    for (int cf = 0; cf < 4; ++cf) {
        const unsigned bRow = (unsigned)(wn * 64 + cf * 16 + l15) * 128;
        #pragma unroll
        for (int s = 0; s < 2; ++s)
            #pragma unroll
            for (int dk = 0; dk < 2; ++dk)
                bfr[cf][s][dk] = *(const bf16x8*)(lds + s * 16384 + bRow +
                                    (((unsigned)(dk * 4) + (unsigned)quad) ^ cx) * 16);
    }
    __syncthreads();
    // ---- B staging pass 2: d-slices 2,3 reuse buf0/buf1
    #pragma unroll
    for (int s = 0; s < 2; ++s)
        #pragma unroll
        for (int j = 0; j < 4; ++j)
            GLOAD_LDS16(gB0 + (s + 2) * 128 + j * 4096, lds + s * 16384 + wvOff + j * 1024);
    __syncthreads();
    #pragma unroll
    for (int cf = 0; cf < 4; ++cf) {
        const unsigned bRow = (unsigned)(wn * 64 + cf * 16 + l15) * 128;
        #pragma unroll
        for (int s = 0; s < 2; ++s)
            #pragma unroll
            for (int dk = 0; dk < 2; ++dk)
                bfr[cf][s + 2][dk] = *(const bf16x8*)(lds + s * 16384 + bRow +
                                    (((unsigned)(dk * 4) + (unsigned)quad) ^ cx) * 16);
    }
    __syncthreads();   // all B reads drained; LDS bufs now free for A pipeline

    // fragment LDS row bases for A (within a 16KB buffer)
    unsigned aR[4];
    #pragma unroll
    for (int rf = 0; rf < 4; ++rf) aR[rf] = (unsigned)(wm * 64 + rf * 16 + l15) * 128;

    unsigned k1[4], k2[4], k3[4];
    #pragma unroll
    for (int cf = 0; cf < 4; ++cf) { k1[cf] = 0xFFFFFFFFu; k2[cf] = 0xFFFFFFFFu; k3[cf] = 0xFFFFFFFFu; }

    // prologue: rounds 0,1 in flight
    ISSUE_A(0, 0u);
    ISSUE_A(1, 16384u);

    unsigned bufR = 0u;   // byte offset of round-r buffer, cycles 0,16384,32768
    for (int mt = 0; mt < MT8 - 1; ++mt) {
        floatx4 acc[4][4];
        #pragma unroll
        for (int rf = 0; rf < 4; ++rf)
            #pragma unroll
            for (int cf = 0; cf < 4; ++cf) acc[rf][cf] = (floatx4){0.f, 0.f, 0.f, 0.f};

        #pragma unroll
        for (int dr = 0; dr < 4; ++dr) {
            VMW4();
            BARR();
            const unsigned bufI = (bufR == 0u) ? 32768u : bufR - 16384u;  // (r+2)%3
            ISSUE_A(mt * 4 + dr + 2, bufI);
            MFMA_ROUND(dr, bufR);
            bufR = (bufR == 32768u) ? 0u : bufR + 16384u;
        }
        TOP3_EPI(mt);
    }
    {   // mt = MT8-1, last 4 rounds (drain tail)
        floatx4 acc[4][4];
        #pragma unroll
        for (int rf = 0; rf < 4; ++rf)
            #pragma unroll
            for (int cf = 0; cf < 4; ++cf) acc[rf][cf] = (floatx4){0.f, 0.f, 0.f, 0.f};

        VMW4(); BARR();
        { const unsigned bufI = (bufR == 0u) ? 32768u : bufR - 16384u; ISSUE_A(4 * MT8 - 2, bufI); }
        MFMA_ROUND(0, bufR);
        bufR = (bufR == 32768u) ? 0u : bufR + 16384u;

        VMW4(); BARR();
        { const unsigned bufI = (bufR == 0u) ? 32768u : bufR - 16384u; ISSUE_A(4 * MT8 - 1, bufI); }
        MFMA_ROUND(1, bufR);
        bufR = (bufR == 32768u) ? 0u : bufR + 16384u;

        VMW4(); BARR();
        MFMA_ROUND(2, bufR);
        bufR = (bufR == 32768u) ? 0u : bufR + 16384u;

        VMW0(); BARR();
        MFMA_ROUND(3, bufR);

        TOP3_EPI(MT8 - 1);
    }

    // merge across row-quads (lanes sharing a token column): xor 16 then xor 32
    #pragma unroll
    for (int cf = 0; cf < 4; ++cf) {
        #pragma unroll
        for (int s = 0; s < 2; ++s) {
            int m = s ? 32 : 16;
            unsigned o1 = (unsigned)__shfl((int)k1[cf], lane ^ m, 64);
            unsigned o2 = (unsigned)__shfl((int)k2[cf], lane ^ m, 64);
            unsigned o3 = (unsigned)__shfl((int)k3[cf], lane ^ m, 64);
            unsigned a1  = umax32(k1[cf], o1);
            k1[cf]       = umin32(k1[cf], o1);
            unsigned b1  = umin32(k2[cf], o2);
            unsigned r3a = umax32(a1, b1);
            k2[cf]       = umin32(a1, b1);
            k3[cf]       = umin32(r3a, umin32(k3[cf], o3));
        }
    }

    __syncthreads();   // staging LDS done; reuse as reduction buffer
    uint4* red = (uint4*)lds;  // 256 entries (wm x 128 tokens)
    if (quad == 0) {
        #pragma unroll
        for (int cf = 0; cf < 4; ++cf)
            red[wm * 128 + wn * 64 + cf * 16 + l15] = make_uint4(k1[cf], k2[cf], k3[cf], 0u);
    }
    __syncthreads();
    if (t < 128) {
        uint4 a = red[t], b = red[128 + t];
        unsigned a1  = umax32(a.x, b.x);
        unsigned r1  = umin32(a.x, b.x);
        unsigned b1  = umin32(a.y, b.y);
        unsigned r3a = umax32(a1, b1);
        unsigned r2  = umin32(a1, b1);
        unsigned r3  = umin32(r3a, umin32(a.z, b.z));
        part[q * NTOK + n0 + t] = make_uint4(r1, r2, r3, 0u);
    }
}

// ---------------------------------------------------------------------------
// rescgath: fused rescore (NCAND=6, near-exact fp32, numpy tie-break) +
// gather (coalesced emb reads, LDS transpose, coalesced BCHW writes).
// 32 tokens/block; phase 1 = 8 iterations x 4 waves (one token per wave);
// winner indices parked in LDS rows[]; phase 2 = gather2 body verbatim.
__global__ void rescgath_kernel(const unsigned short* __restrict__ zh,
                                const unsigned short* __restrict__ zl,
                                const float* __restrict__ emb,
                                const float* __restrict__ eSq, const uint4* __restrict__ part,
                                float* __restrict__ out, float* __restrict__ idxF) {
    __shared__ float tile[32 * 260];
    __shared__ int rows[32];
    const int t    = threadIdx.x;
    const int lane = t & 63;
    const int wv   = t >> 6;
    const int n0   = blockIdx.x * 32;

    // ---- phase 1: rescore 32 tokens (8 per wave, sequential)
    for (int it = 0; it < 8; ++it) {
        const int tl = it * 4 + wv;       // local token 0..31
        const int n  = n0 + tl;
        int c[NCAND];
        #pragma unroll
        for (int s = 0; s < MSPLIT; ++s) {
            uint4 p = part[s * NTOK + n];
            c[3 * s]     = s * STRIP + (int)(p.x & 0xFFFu);
            c[3 * s + 1] = s * STRIP + (int)(p.y & 0xFFFu);
            c[3 * s + 2] = s * STRIP + (int)(p.z & 0xFFFu);
        }
        ushort4 h = *(const ushort4*)&zh[(size_t)n * CDIM + lane * 4];
        ushort4 l = *(const ushort4*)&zl[(size_t)n * CDIM + lane * 4];
        float z0 = __uint_as_float((unsigned)h.x << 16) + __uint_as_float((unsigned)l.x << 16);
        float z1 = __uint_as_float((unsigned)h.y << 16) + __uint_as_float((unsigned)l.y << 16);
        float z2 = __uint_as_float((unsigned)h.z << 16) + __uint_as_float((unsigned)l.z << 16);
        float z3 = __uint_as_float((unsigned)h.w << 16) + __uint_as_float((unsigned)l.w << 16);
        float acc[NCAND];
        #pragma unroll
        for (int s = 0; s < NCAND; ++s) {
            float4 e = *(const float4*)&emb[(size_t)c[s] * CDIM + lane * 4];
            acc[s] = fmaf(z0, e.x, fmaf(z1, e.y, fmaf(z2, e.z, z3 * e.w)));
        }
        #pragma unroll
        for (int off = 32; off; off >>= 1) {
            #pragma unroll
            for (int s = 0; s < NCAND; ++s) acc[s] += __shfl_down(acc[s], off);
        }
        if (lane == 0) {
            float bd = 3.4e38f; int bi = 0x7fffffff;
            #pragma unroll
            for (int s = 0; s < NCAND; ++s) {
                float dv = eSq[c[s]] - 2.f * acc[s];
                if (dv < bd || (dv == bd && c[s] < bi)) { bd = dv; bi = c[s]; }
            }
            rows[tl] = bi;
            idxF[n]  = (float)bi;
        }
    }
    __syncthreads();

    // ---- phase 2: gather + transpose + coalesced BCHW writes
    {
        int r  = t >> 3;
        int c0 = (t & 7) * 32;
        const float* src = emb + (size_t)rows[r] * CDIM + c0;
        #pragma unroll
        for (int j = 0; j < 8; ++j) {
            float4 v = *(const float4*)(src + j * 4);
            *(float4*)&tile[r * 260 + c0 + j * 4] = v;
        }
    }
    __syncthreads();
    const int b   = n0 >> 10;
    const int hw0 = n0 & 1023;
    const int cg  = t >> 3;         // 0..31
    const int h4  = (t & 7) * 4;    // 0..28
    #pragma unroll
    for (int j = 0; j < 8; ++j) {
        int c = cg + j * 32;
        float4 v;
        v.x = tile[(h4 + 0) * 260 + c];
        v.y = tile[(h4 + 1) * 260 + c];
        v.z = tile[(h4 + 2) * 260 + c];
        v.w = tile[(h4 + 3) * 260 + c];
        *(float4*)&out[((size_t)b << 18) | ((size_t)c << 10) | (size_t)(hw0 + h4)] = v;
    }
}

// ---------------------------------------------------------------------------
// gather2 (fallback path): coalesced emb reads, LDS transpose, BCHW writes
__global__ void gather2_kernel(const float* __restrict__ emb, const int* __restrict__ idx,
                               float* __restrict__ out) {
    __shared__ float tile[32 * 260];
    __shared__ int rows[32];
    const int t  = threadIdx.x;
    const int n0 = blockIdx.x * 32;
    if (t < 32) rows[t] = idx[n0 + t];
    __syncthreads();
    {
        int r  = t >> 3;
        int c0 = (t & 7) * 32;
        const float* src = emb + (size_t)rows[r] * CDIM + c0;
        #pragma unroll
        for (int j = 0; j < 8; ++j) {
            float4 v = *(const float4*)(src + j * 4);
            *(float4*)&tile[r * 260 + c0 + j * 4] = v;
        }
    }
    __syncthreads();
    const int b   = n0 >> 10;
    const int hw0 = n0 & 1023;
    const int cg  = t >> 3;         // 0..31
    const int h4  = (t & 7) * 4;    // 0..28
    #pragma unroll
    for (int j = 0; j < 8; ++j) {
        int c = cg + j * 32;
        float4 v;
        v.x = tile[(h4 + 0) * 260 + c];
        v.y = tile[(h4 + 1) * 260 + c];
        v.z = tile[(h4 + 2) * 260 + c];
        v.w = tile[(h4 + 3) * 260 + c];
        *(float4*)&out[((size_t)b << 18) | ((size_t)c << 10) | (size_t)(hw0 + h4)] = v;
    }
}

// ---------------------------------------------------------------------------
// Fallback: round-1 fp32 path (used only if ws is too small for fast path)
#define F_BM  128
#define F_BK  128
#define F_BD  32
#define F_BSS (F_BK + 4)
#define F_KSPLIT 4
#define F_KPER  (KEMB / F_KSPLIT)
#define FWS_ESQ 0
#define FWS_PV  32768
#define FWS_PI  557056
#define FWS_IDX 1081344

__global__ void esq_kernel(const float* __restrict__ emb, float* __restrict__ eSq) {
    int k    = blockIdx.x * 4 + (threadIdx.x >> 6);
    int lane = threadIdx.x & 63;
    float4 v = *(const float4*)&emb[k * CDIM + lane * 4];
    float s  = v.x * v.x + v.y * v.y + v.z * v.z + v.w * v.w;
    #pragma unroll
    for (int off = 32; off; off >>= 1) s += __shfl_down(s, off);
    if (lane == 0) eSq[k] = s;
}

__global__ void dist_kernel(const float* __restrict__ z, const float* __restrict__ emb,
                            const float* __restrict__ eSq,
                            float* __restrict__ pv, int* __restrict__ pi) {
    __shared__ __align__(16) char smem[(F_BD * F_BM + F_BD * F_BSS) * 4];
    float (*As)[F_BM]  = (float (*)[F_BM])smem;
    float (*Bs)[F_BSS] = (float (*)[F_BSS])(smem + F_BD * F_BM * 4);
    const int t = threadIdx.x, tx = t & 15, ty = t >> 4;
    const int rb = blockIdx.x & 255, q = blockIdx.x >> 8;
    const int m0 = rb * F_BM, bb = m0 >> 10, hw0 = m0 & 1023;
    float minv[8]; int mini[8];
    #pragma unroll
    for (int i = 0; i < 8; ++i) { minv[i] = 3.4028235e38f; mini[i] = 0; }
    const int kbeg = q * F_KPER;
    for (int k0 = kbeg; k0 < kbeg + F_KPER; k0 += F_BK) {
        float acc[8][8];
        #pragma unroll
        for (int r = 0; r < 8; ++r)
            #pragma unroll
            for (int c = 0; c < 8; ++c) acc[r][c] = 0.f;
        for (int d0 = 0; d0 < CDIM; d0 += F_BD) {
            __syncthreads();
            #pragma unroll
            for (int i = 0; i < 4; ++i) {
                int u = t + i * 256; int m4 = (u & 31) << 2; int cR = u >> 5;
                float4 v = *(const float4*)&z[(bb << 18) + ((d0 + cR) << 10) + hw0 + m4];
                *(float4*)&As[cR][m4] = v;
            }
            #pragma unroll
            for (int i = 0; i < 4; ++i) {
                int u = t + i * 256; int kR = u >> 3; int c4 = (u & 7) << 2;
                float4 v = *(const float4*)&emb[(k0 + kR) * CDIM + d0 + c4];
                Bs[c4 + 0][kR] = v.x; Bs[c4 + 1][kR] = v.y;
                Bs[c4 + 2][kR] = v.z; Bs[c4 + 3][kR] = v.w;
            }
            __syncthreads();
            #pragma unroll
            for (int d = 0; d < F_BD; ++d) {
                float a[8], bb2[8];
                *(float4*)&a[0] = *(const float4*)&As[d][(ty << 2)];
                *(float4*)&a[4] = *(const float4*)&As[d][64 + (ty << 2)];
                *(float4*)&bb2[0] = *(const float4*)&Bs[d][(tx << 2)];
                *(float4*)&bb2[4] = *(const float4*)&Bs[d][64 + (tx << 2)];
                #pragma unroll
                for (int r = 0; r < 8; ++r)
                    #pragma unroll
                    for (int c = 0; c < 8; ++c) acc[r][c] = fmaf(a[r], bb2[c], acc[r][c]);
            }
        }
        #pragma unroll
        for (int c = 0; c < 8; ++c) {
            int kk = (c < 4) ? ((tx << 2) + c) : (64 + (tx << 2) + (c - 4));
            int kg = k0 + kk;
            float es = eSq[kg];
            #pragma unroll
            for (int r = 0; r < 8; ++r) {
                float v = fmaf(-2.f, acc[r][c], es);
                if (v < minv[r]) { minv[r] = v; mini[r] = kg; }
            }
        }
    }
    __syncthreads();
    float (*redV)[16] = (float (*)[16])smem;
    int   (*redI)[16] = (int   (*)[16])(smem + F_BM * 16 * 4);
    #pragma unroll
    for (int r = 0; r < 8; ++r) {
        int row = (r < 4) ? ((ty << 2) + r) : (64 + (ty << 2) + (r - 4));
        redV[row][tx] = minv[r]; redI[row][tx] = mini[r];
    }
    __syncthreads();
    if (t < F_BM) {
        float bv = redV[t][0]; int bi = redI[t][0];
        #pragma unroll
        for (int i = 1; i < 16; ++i) {
            float v = redV[t][i]; int ii = redI[t][i];
            if (v < bv || (v == bv && ii < bi)) { bv = v; bi = ii; }
        }
        int n = m0 + t;
        pv[q * NTOK + n] = bv; pi[q * NTOK + n] = bi;
    }
}

__global__ void merge_kernel(const float* __restrict__ pv, const int* __restrict__ pi,
                             int* __restrict__ idxOut, float* __restrict__ idxFOut) {
    int n = blockIdx.x * 256 + threadIdx.x;
    float bv = pv[n]; int bi = pi[n];
    #pragma unroll
    for (int q = 1; q < F_KSPLIT; ++q) {
        float v = pv[q * NTOK + n]; int ii = pi[q * NTOK + n];
        if (v < bv || (v == bv && ii < bi)) { bv = v; bi = ii; }
    }
    idxOut[n] = bi; idxFOut[n] = (float)bi;
}

// ---------------------------------------------------------------------------
extern "C" void kernel_launch(void* const* d_in, const int* in_sizes, int n_in,
                              void* d_out, int out_size, void* d_ws, size_t ws_size,
                              hipStream_t stream) {
    const float* z   = (const float*)d_in[0];
    const float* emb = (const float*)d_in[1];
    float* out = (float*)d_out;
    char*  ws  = (char*)d_ws;

    if (ws_size >= WS8_TOTAL) {
        float*          eSq  = (float*)(ws + WS8_ESQ);
        float*          eqm  = (float*)(ws + WS8_EQM);
        unsigned short* eh   = (unsigned short*)(ws + WS8_EH);
        unsigned short* zh   = (unsigned short*)(ws + WS8_ZH);
        unsigned short* zl   = (unsigned short*)(ws + WS8_ZL);
        uint4*          part = (uint4*)(ws + WS8_PART);

        prep_kernel   <<<4096, 256, 0, stream>>>(z, emb, eSq, eqm, eh, zh, zl);
        dist8_kernel  <<<256 * MSPLIT, 256, 0, stream>>>(zh, eh, eqm, part);
        rescgath_kernel<<<NTOK / 32, 256, 0, stream>>>(zh, zl, emb, eSq, part, out, out + ZQ_SIZE);
    } else {
        float* eSq = (float*)(ws + FWS_ESQ);
        float* pv  = (float*)(ws + FWS_PV);
        int*   pi  = (int*)(ws + FWS_PI);
        int*   idx = (int*)(ws + FWS_IDX);
        esq_kernel  <<<KEMB / 4, 256, 0, stream>>>(emb, eSq);
        dist_kernel <<<256 * F_KSPLIT, 256, 0, stream>>>(z, emb, eSq, pv, pi);
        merge_kernel<<<NTOK / 256, 256, 0, stream>>>(pv, pi, idx, out + ZQ_SIZE);
        gather2_kernel<<<NTOK / 32, 256, 0, stream>>>(emb, idx, out);
    }
}